// Round 1
// baseline (354.443 us; speedup 1.0000x reference)
//
#include <hip/hip_runtime.h>
#include <math.h>

#define NBINS 128

__device__ __forceinline__ float block_reduce_sum(float v, float* scratch, int tid) {
    // 256 threads = 4 waves of 64
    #pragma unroll
    for (int off = 32; off > 0; off >>= 1) v += __shfl_down(v, off);
    if ((tid & 63) == 0) scratch[tid >> 6] = v;
    __syncthreads();
    float r = scratch[0] + scratch[1] + scratch[2] + scratch[3];
    __syncthreads();
    return r;
}

__global__ __launch_bounds__(256) void sift_desc_kernel(
        const float* __restrict__ in, float* __restrict__ out) {
    __shared__ float patch[32 * 32];
    __shared__ float desc[NBINS];
    __shared__ float scratch[4];

    const int b   = blockIdx.x;
    const int tid = threadIdx.x;

    // stage patch: 1024 floats, 256 threads x float4
    {
        const float4* src = reinterpret_cast<const float4*>(in + (size_t)b * 1024);
        reinterpret_cast<float4*>(patch)[tid] = src[tid];
    }
    if (tid < NBINS) desc[tid] = 0.0f;
    __syncthreads();

    constexpr float EPS   = 1e-10f;
    constexpr float TWOPI = 6.28318530717958647692f;
    constexpr float K8    = 8.0f / TWOPI;           // map ori -> bin space
    constexpr float GEXP  = -1.0f / 1024.0f;        // -(1/(2*sigma^2)), 2*sigma^2 = 1024

    #pragma unroll
    for (int i = 0; i < 4; ++i) {
        const int p = tid + i * 256;
        const int y = p >> 5, x = p & 31;
        const int xm = (x > 0) ? x - 1 : 0,  xp = (x < 31) ? x + 1 : 31;
        const int ym = (y > 0) ? y - 1 : 0,  yp = (y < 31) ? y + 1 : 31;
        const float gx = 0.5f * (patch[y * 32 + xp] - patch[y * 32 + xm]);
        const float gy = 0.5f * (patch[yp * 32 + x] - patch[ym * 32 + x]);

        const float dx = (float)x - 15.5f, dy = (float)y - 15.5f;
        const float gw  = __expf((dx * dx + dy * dy) * GEXP);   // unnormalized gaussian (scale cancels in l2norm)
        const float mag = sqrtf(gx * gx + gy * gy + EPS) * gw;

        const float ori  = atan2f(gy, gx + EPS) + TWOPI;        // (pi, 3pi]
        const float obig = ori * K8;                            // [4, 12]
        const float b0f  = floorf(obig);
        const float w1   = obig - b0f;
        const int  bin0  = ((int)b0f) & 7;
        const int  bin1  = (bin0 + 1) & 7;
        const float m1 = w1 * mag;
        const float m0 = (1.0f - w1) * mag;

        // spatial pooling scatter: conv ksize=12, stride=8, pad=3.
        // candidate A: ox = (x+3)>>3, k = (x+3)&7 (always in [0,8) -> valid weight)
        // candidate B: ox-1,        k+8 in [8,12) valid iff (x+3)&7 < 4
        const int   kxA = (x + 3) & 7,  oxA = (x + 3) >> 3;
        const int   kyA = (y + 3) & 7,  oyA = (y + 3) >> 3;
        const float wxA = 6.0f - fabsf((float)kxA - 5.5f);      // triangular (unnormalized; /36 cancels)
        const float wyA = 6.0f - fabsf((float)kyA - 5.5f);
        const float wxB = 6.0f - fabsf((float)(kxA + 8) - 5.5f);
        const float wyB = 6.0f - fabsf((float)(kyA + 8) - 5.5f);
        const bool  vxA = (oxA < 4);
        const bool  vyA = (oyA < 4);
        const bool  vxB = (oxA > 0) && (kxA < 4);
        const bool  vyB = (oyA > 0) && (kyA < 4);

        #pragma unroll
        for (int jy = 0; jy < 2; ++jy) {
            const bool  vy = jy ? vyB : vyA;
            if (!vy) continue;
            const int   oy = jy ? (oyA - 1) : oyA;
            const float wy = jy ? wyB : wyA;
            #pragma unroll
            for (int jx = 0; jx < 2; ++jx) {
                const bool  vx = jx ? vxB : vxA;
                if (!vx) continue;
                const int   ox = jx ? (oxA - 1) : oxA;
                const float wx = jx ? wxB : wxA;
                const float wxy = wx * wy;
                const int base = oy * 4 + ox;
                atomicAdd(&desc[bin0 * 16 + base], m0 * wxy);
                atomicAdd(&desc[bin1 * 16 + base], m1 * wxy);
            }
        }
    }
    __syncthreads();

    // normalization chain: l2 -> clip(0,0.2) -> l2 -> l1 -> sqrt(+eps)
    float v = (tid < NBINS) ? desc[tid] : 0.0f;

    float s2 = block_reduce_sum(v * v, scratch, tid);
    v = v / fmaxf(sqrtf(s2), 1e-12f);
    v = fminf(fmaxf(v, 0.0f), 0.2f);

    float s2b = block_reduce_sum(v * v, scratch, tid);
    v = v / fmaxf(sqrtf(s2b), 1e-12f);

    float s1 = block_reduce_sum(v, scratch, tid);   // v >= 0, so L1 == sum
    v = sqrtf(v / fmaxf(s1, 1e-12f) + EPS);

    if (tid < NBINS) out[(size_t)b * NBINS + tid] = v;
}

extern "C" void kernel_launch(void* const* d_in, const int* in_sizes, int n_in,
                              void* d_out, int out_size, void* d_ws, size_t ws_size,
                              hipStream_t stream) {
    const float* in = (const float*)d_in[0];
    float* out = (float*)d_out;
    const int batch = in_sizes[0] / 1024;   // 32*32 per patch
    sift_desc_kernel<<<batch, 256, 0, stream>>>(in, out);
}

// Round 2
// 69.448 us; speedup vs baseline: 5.1038x; 5.1038x over previous
//
#include <hip/hip_runtime.h>
#include <math.h>

#define NBINS 128

__device__ __forceinline__ float block_reduce_sum(float v, float* scratch, int tid) {
    // 256 threads = 4 waves of 64
    #pragma unroll
    for (int off = 32; off > 0; off >>= 1) v += __shfl_down(v, off);
    if ((tid & 63) == 0) scratch[tid >> 6] = v;
    __syncthreads();
    float r = scratch[0] + scratch[1] + scratch[2] + scratch[3];
    __syncthreads();
    return r;
}

__global__ __launch_bounds__(256) void sift_desc_kernel(
        const float* __restrict__ in, float* __restrict__ out) {
    // smem union: phase0 = patch[32][32] (row-major, y*32+x)
    //             phase1+ = rowpart[y*33 + 4*a + ox]  (32 rows x (8 ang x 4 ox), padded)
    __shared__ float  smem[1056];
    __shared__ float4 pix[32][33];   // (m0, m1, bin0f, pad) per pixel, padded row stride
    __shared__ float  scratch[4];

    const int b   = blockIdx.x;
    const int tid = threadIdx.x;

    // ---- stage patch: 1024 floats via float4 ----
    reinterpret_cast<float4*>(smem)[tid] =
        reinterpret_cast<const float4*>(in + (size_t)b * 1024)[tid];
    __syncthreads();

    constexpr float EPS = 1e-10f;

    // ---- phase 0: gradient -> weighted magnitude + angular soft-binning ----
    #pragma unroll
    for (int i = 0; i < 4; ++i) {
        const int p = tid + i * 256;
        const int y = p >> 5, x = p & 31;
        const float gx = 0.5f * (smem[y * 32 + ((x < 31) ? x + 1 : 31)] -
                                 smem[y * 32 + ((x > 0) ? x - 1 : 0)]);
        const float gy = 0.5f * (smem[((y < 31) ? y + 1 : 31) * 32 + x] -
                                 smem[((y > 0) ? y - 1 : 0) * 32 + x]);

        const float dx = (float)x - 15.5f, dy = (float)y - 15.5f;
        const float gw  = __expf((dx * dx + dy * dy) * (-1.0f / 1024.0f)); // unnormalized (cancels in l2)
        const float mag = __builtin_amdgcn_sqrtf(fmaf(gx, gx, fmaf(gy, gy, EPS))) * gw;

        // cheap atan2 in "bin units": obig = 4/pi * atan2(gy, gx+eps) + 8
        const float gxe = gx + EPS;
        const float ax = fabsf(gxe), ay = fabsf(gy);
        const float mx = fmaxf(ax, ay), mn = fminf(ax, ay);
        const float t  = mn * __builtin_amdgcn_rcpf(fmaxf(mx, 1e-35f));
        const float s  = t * t;
        float pl = fmaf(s, -0.0117212f, 0.05265332f);
        pl = fmaf(s, pl, -0.11643287f);
        pl = fmaf(s, pl, 0.19354346f);
        pl = fmaf(s, pl, -0.33262347f);
        pl = fmaf(s, pl, 0.99997726f);
        float atb = t * pl * 1.27323954473516268f;   // *4/pi -> [0,1]
        atb = (ay > ax)    ? 2.0f - atb : atb;
        atb = (gxe < 0.0f) ? 4.0f - atb : atb;
        atb = (gy  < 0.0f) ? -atb       : atb;
        const float obig = atb + 8.0f;               // [4, 12]
        const float b0f  = floorf(obig);
        const float w1   = obig - b0f;
        const int bin0   = ((int)b0f) & 7;

        pix[y][x] = make_float4(mag * (1.0f - w1), mag * w1, (float)bin0, 0.0f);
    }
    __syncthreads();   // patch reads done; smem becomes rowpart

    // ---- phase 1: x-pooling. thread (y, a) -> rowpart[y][a][0..3] ----
    {
        const int y1 = tid >> 3, a = tid & 7;
        const float af = (float)a;
        float rp[4] = {0.f, 0.f, 0.f, 0.f};
        #pragma unroll
        for (int x = 0; x < 32; ++x) {
            const float4 q = pix[y1][x];
            const float b1f = (q.z == 7.0f) ? 0.0f : q.z + 1.0f;
            const float c = ((q.z == af) ? q.x : 0.0f) + ((b1f == af) ? q.y : 0.0f);
            const int kx  = (x + 3) & 7;
            const int oxA = (x + 3) >> 3;
            const float wA = 6.0f - fabsf((float)kx - 5.5f);          // compile-time
            const float wB = 6.0f - fabsf((float)(kx + 8) - 5.5f);    // compile-time
            if (oxA < 4)            rp[oxA]     += c * wA;   // compile-time branch/index
            if (kx < 4 && oxA > 0)  rp[oxA - 1] += c * wB;
        }
        float* rowp = smem + y1 * 33 + 4 * a;
        rowp[0] = rp[0]; rowp[1] = rp[1]; rowp[2] = rp[2]; rowp[3] = rp[3];
    }
    __syncthreads();

    // ---- phase 2: y-pooling. 128 threads, one output bin each ----
    float v = 0.0f;
    if (tid < NBINS) {
        const int oy = (tid >> 2) & 3, ox = tid & 3;
        const int a2 = tid >> 4;
        const float* rpb = smem + 4 * a2 + ox;
        const int y0 = oy * 8 - 3;
        #pragma unroll
        for (int k = 0; k < 12; ++k) {
            const float wk = 6.0f - fabsf((float)k - 5.5f);   // compile-time
            const int y = y0 + k;
            const int yc = (y < 0) ? 0 : ((y > 31) ? 31 : y);
            const float w = (y == yc) ? wk : 0.0f;
            v = fmaf(w, rpb[yc * 33], v);
        }
    }

    // ---- normalization chain: l2 -> clip(0, 0.2) -> l2 -> l1 -> sqrt(+eps) ----
    float s2 = block_reduce_sum(v * v, scratch, tid);
    v = v / fmaxf(__builtin_amdgcn_sqrtf(s2), 1e-12f);
    v = fminf(fmaxf(v, 0.0f), 0.2f);

    float s2b = block_reduce_sum(v * v, scratch, tid);
    v = v / fmaxf(__builtin_amdgcn_sqrtf(s2b), 1e-12f);

    float s1 = block_reduce_sum(v, scratch, tid);   // v >= 0 -> L1 == sum
    v = __builtin_amdgcn_sqrtf(v / fmaxf(s1, 1e-12f) + EPS);

    if (tid < NBINS) out[(size_t)b * NBINS + tid] = v;
}

extern "C" void kernel_launch(void* const* d_in, const int* in_sizes, int n_in,
                              void* d_out, int out_size, void* d_ws, size_t ws_size,
                              hipStream_t stream) {
    const float* in = (const float*)d_in[0];
    float* out = (float*)d_out;
    const int batch = in_sizes[0] / 1024;   // 32*32 per patch
    sift_desc_kernel<<<batch, 256, 0, stream>>>(in, out);
}

// Round 4
// 49.311 us; speedup vs baseline: 7.1880x; 1.4084x over previous
//
#include <hip/hip_runtime.h>
#include <math.h>

typedef __attribute__((ext_vector_type(8))) short bf16x8;
typedef __attribute__((ext_vector_type(4))) float f32x4;

// triangular x-pooling table WXT[n][x] (bf16 bits); conv ksize=12, stride=8, pad=3
struct alignas(16) WxTbl { unsigned short v[16 * 32]; };

static constexpr WxTbl gen_wx() {
    WxTbl t{};
    for (int n = 0; n < 16; ++n)
        for (int x = 0; x < 32; ++x) {
            float w = 0.0f;
            if (n < 4) {
                int kx = x - 8 * n + 3;
                if (kx >= 0 && kx < 12) {
                    float d = (float)kx - 5.5f; if (d < 0) d = -d;
                    w = 6.0f - d;               // unnormalized tri; scale cancels in l2norm
                }
            }
            t.v[n * 32 + x] = (unsigned short)(__builtin_bit_cast(unsigned int, w) >> 16);
        }
    return t;
}

__device__ const WxTbl WXT = gen_wx();

__device__ __forceinline__ float block_reduce_sum(float v, float* scratch, int tid) {
    #pragma unroll
    for (int off = 32; off > 0; off >>= 1) v += __shfl_down(v, off);
    if ((tid & 63) == 0) scratch[tid >> 6] = v;
    __syncthreads();
    float r = scratch[0] + scratch[1] + scratch[2] + scratch[3];
    __syncthreads();
    return r;
}

#define R2S 36   // r2f row stride (floats): rows 16B-aligned, 4-bank rotation

__global__ __launch_bounds__(256) void sift_desc_kernel(
        const float* __restrict__ in, float* __restrict__ out) {
    __shared__ float patch[1024];
    __shared__ __align__(16) unsigned short ang[256 * 32]; // [bin*32+y][x], bf16, LINEAR
    __shared__ __align__(16) float r2f[32 * R2S];          // [a*4+ox][y], f32
    __shared__ float scratch[4];

    const int b = blockIdx.x, tid = threadIdx.x;

    reinterpret_cast<float4*>(patch)[tid] =
        reinterpret_cast<const float4*>(in + (size_t)b * 1024)[tid];
    {
        const float4 z = make_float4(0.f, 0.f, 0.f, 0.f);
        float4* az = reinterpret_cast<float4*>(ang);
        az[tid] = z; az[tid + 256] = z; az[tid + 512] = z; az[tid + 768] = z;
    }
    __syncthreads();

    constexpr float EPS = 1e-10f;

    // ---- phase 0: gradient -> weighted magnitude -> angular soft-bin scatter ----
    #pragma unroll
    for (int i = 0; i < 4; ++i) {
        const int p = tid + i * 256;
        const int y = p >> 5, x = p & 31;
        const float gx = 0.5f * (patch[y * 32 + ((x < 31) ? x + 1 : 31)] -
                                 patch[y * 32 + ((x > 0) ? x - 1 : 0)]);
        const float gy = 0.5f * (patch[((y < 31) ? y + 1 : 31) * 32 + x] -
                                 patch[((y > 0) ? y - 1 : 0) * 32 + x]);
        const float dx = (float)x - 15.5f, dy = (float)y - 15.5f;
        const float gw  = __expf((dx * dx + dy * dy) * (-1.0f / 1024.0f));
        const float mag = __builtin_amdgcn_sqrtf(fmaf(gy, gy, fmaf(gx, gx, EPS))) * gw;

        const float gxe = gx + EPS;
        const float ax = fabsf(gxe), ay = fabsf(gy);
        const float mx = fmaxf(ax, ay), mn = fminf(ax, ay);
        const float t = mn * __builtin_amdgcn_rcpf(fmaxf(mx, 1e-35f));
        const float s = t * t;
        float pl = fmaf(s, -0.0117212f, 0.05265332f);
        pl = fmaf(s, pl, -0.11643287f);
        pl = fmaf(s, pl, 0.19354346f);
        pl = fmaf(s, pl, -0.33262347f);
        pl = fmaf(s, pl, 0.99997726f);
        float atb = t * pl * 1.27323954473516268f;
        atb = (ay > ax)    ? 2.0f - atb : atb;
        atb = (gxe < 0.0f) ? 4.0f - atb : atb;
        atb = (gy  < 0.0f) ? -atb       : atb;
        const float obig = atb + 8.0f;
        const float b0f  = floorf(obig);
        const float w1   = obig - b0f;
        const int bin0 = ((int)b0f) & 7;
        const int bin1 = (bin0 + 1) & 7;
        const float m1 = w1 * mag;
        const float m0 = mag - m1;
        ang[(bin0 * 32 + y) * 32 + x] =
            (unsigned short)((__builtin_bit_cast(unsigned int, m0) + 0x8000u) >> 16);
        ang[(bin1 * 32 + y) * 32 + x] =
            (unsigned short)((__builtin_bit_cast(unsigned int, m1) + 0x8000u) >> 16);
    }
    __syncthreads();

    // ---- GEMM1 (MFMA): x-pooling. A = ang (256x32), B^T = WXT (16x32) ----
    {
        const int l = tid & 63, w = tid >> 6, g = l >> 4, n = l & 15;
        const bf16x8 bfrag = *reinterpret_cast<const bf16x8*>(WXT.v + n * 32 + g * 8);
        const f32x4 zacc = {0.f, 0.f, 0.f, 0.f};
        #pragma unroll
        for (int tt = 0; tt < 4; ++tt) {
            const int T = w * 4 + tt;   // row tile 0..15
            const bf16x8 afrag = *reinterpret_cast<const bf16x8*>(
                ang + (T * 16 + n) * 32 + g * 8);
            const f32x4 acc = __builtin_amdgcn_mfma_f32_16x16x32_bf16(afrag, bfrag, zacc, 0, 0, 0);
            if (n < 4) {
                // C layout: row = T*16 + 4g + reg, col = n (=ox)
                const int row = T * 16 + 4 * g;
                const int a = row >> 5, y0 = row & 31;
                *reinterpret_cast<float4*>(r2f + (a * 4 + n) * R2S + y0) =
                    make_float4(acc[0], acc[1], acc[2], acc[3]);
            }
        }
    }
    __syncthreads();

    // ---- phase 2: y-pooling (plain VALU, round-2-verified pattern) ----
    float v = 0.0f;
    if (tid < 128) {
        const int a = tid >> 4, oy = (tid >> 2) & 3, ox = tid & 3;
        const float* rp = r2f + (a * 4 + ox) * R2S;
        const int y0 = oy * 8 - 3;
        #pragma unroll
        for (int k = 0; k < 12; ++k) {
            const float wk = 6.0f - fabsf((float)k - 5.5f);   // compile-time
            const int yy = y0 + k;
            const int yc = (yy < 0) ? 0 : ((yy > 31) ? 31 : yy);
            const float wv = (yy == yc) ? wk : 0.0f;
            v = fmaf(wv, rp[yc], v);
        }
    }

    // ---- normalization chain: l2 -> clip(0,0.2) -> l2 -> l1 -> sqrt(+eps) ----
    float s2 = block_reduce_sum(v * v, scratch, tid);
    v = v / fmaxf(__builtin_amdgcn_sqrtf(s2), 1e-12f);
    v = fminf(fmaxf(v, 0.0f), 0.2f);
    float s2b = block_reduce_sum(v * v, scratch, tid);
    v = v / fmaxf(__builtin_amdgcn_sqrtf(s2b), 1e-12f);
    float s1 = block_reduce_sum(v, scratch, tid);
    v = __builtin_amdgcn_sqrtf(v / fmaxf(s1, 1e-12f) + EPS);

    if (tid < 128) out[(size_t)b * 128 + tid] = v;
}

extern "C" void kernel_launch(void* const* d_in, const int* in_sizes, int n_in,
                              void* d_out, int out_size, void* d_ws, size_t ws_size,
                              hipStream_t stream) {
    const float* in = (const float*)d_in[0];
    float* out = (float*)d_out;
    const int batch = in_sizes[0] / 1024;   // 32*32 per patch
    sift_desc_kernel<<<batch, 256, 0, stream>>>(in, out);
}

// Round 6
// 42.366 us; speedup vs baseline: 8.3662x; 1.1639x over previous
//
#include <hip/hip_runtime.h>
#include <math.h>

typedef __attribute__((ext_vector_type(8))) short bf16x8;
typedef __attribute__((ext_vector_type(4))) float f32x4;

// triangular x-pooling table WXT[n][x] (bf16 bits); conv ksize=12, stride=8, pad=3
struct alignas(16) WxTbl { unsigned short v[16 * 32]; };

static constexpr WxTbl gen_wx() {
    WxTbl t{};
    for (int n = 0; n < 16; ++n)
        for (int x = 0; x < 32; ++x) {
            float w = 0.0f;
            if (n < 4) {
                int kx = x - 8 * n + 3;
                if (kx >= 0 && kx < 12) {
                    float d = (float)kx - 5.5f; if (d < 0) d = -d;
                    w = 6.0f - d;               // unnormalized tri; scale cancels in l2norm
                }
            }
            t.v[n * 32 + x] = (unsigned short)(__builtin_bit_cast(unsigned int, w) >> 16);
        }
    return t;
}

__device__ const WxTbl WXT = gen_wx();

__device__ __forceinline__ float block_reduce_sum(float v, float* scratch, int tid) {
    if (tid < 128) {
        #pragma unroll
        for (int off = 32; off > 0; off >>= 1) v += __shfl_down(v, off);
    }
    if ((tid & 63) == 0 && tid < 128) scratch[tid >> 6] = v;
    __syncthreads();
    float r = scratch[0] + scratch[1];
    __syncthreads();
    return r;
}

#define R2S 36   // r2f row stride (floats)

__global__ __launch_bounds__(256) void sift_desc_kernel(
        const float* __restrict__ in, float* __restrict__ out) {
    __shared__ __align__(16) unsigned short ang[8192];  // [bin*32+y][x] bf16, 16 KB, LINEAR
    __shared__ __align__(16) float ubuf[32 * R2S];      // union: patch[1024] (phase0) / r2f (phase2)
    __shared__ float scratch[2];

    const int b = blockIdx.x, tid = threadIdx.x;
    float* patch = ubuf;
    float* r2f   = ubuf;

    // stage patch (float4) + zero-fill ang
    reinterpret_cast<float4*>(patch)[tid] =
        reinterpret_cast<const float4*>(in + (size_t)b * 1024)[tid];
    {
        const float4 z = make_float4(0.f, 0.f, 0.f, 0.f);
        float4* az = reinterpret_cast<float4*>(ang);
        az[tid] = z; az[tid + 256] = z; az[tid + 512] = z; az[tid + 768] = z;
    }
    __syncthreads();

    constexpr float EPS = 1e-10f;

    // ---- phase 0: row-segment gradients -> weighted mag -> angular soft-bin scatter ----
    {
        const int r  = tid >> 3;          // row 0..31
        const int sg = tid & 7;           // segment 0..7
        const int x0 = sg * 4;
        const float4 cur = *reinterpret_cast<const float4*>(patch + r * 32 + x0);
        const int rup = (r > 0) ? r - 1 : 0, rdn = (r < 31) ? r + 1 : 31;
        const float4 up = *reinterpret_cast<const float4*>(patch + rup * 32 + x0);
        const float4 dn = *reinterpret_cast<const float4*>(patch + rdn * 32 + x0);
        const float lfs = __shfl_up(cur.w, 1);
        const float rts = __shfl_down(cur.x, 1);
        const float lf = (sg == 0) ? cur.x : lfs;   // replicate-pad at x=0
        const float rt = (sg == 7) ? cur.w : rts;   // replicate-pad at x=31

        // u = 2*gx, v = 2*gy (0.5 folded into mag); EPS scaled accordingly
        const float u0 = cur.y - lf,    v0 = dn.x - up.x;
        const float u1 = cur.z - cur.x, v1 = dn.y - up.y;
        const float u2 = cur.w - cur.y, v2 = dn.z - up.z;
        const float u3 = rt    - cur.z, v3 = dn.w - up.w;
        const float uu[4] = {u0, u1, u2, u3};
        const float vv[4] = {v0, v1, v2, v3};

        const float fy = (float)r - 15.5f;
        const float ky = fy * fy;
        const float d0 = (float)x0 - 15.5f;
        constexpr float C2 = -1.44269504089f / 1024.0f;   // exp2 scale for gaussian
        const int base2 = (r * 32 + x0) * 2;
        char* angb = reinterpret_cast<char*>(ang);

        #pragma unroll
        for (int i = 0; i < 4; ++i) {
            const float u = uu[i], v = vv[i];
            const float dx = d0 + (float)i;
            const float gw = __builtin_amdgcn_exp2f(fmaf(dx, dx, ky) * C2);
            // mag = sqrt(gx^2+gy^2+EPS)*gw, gx=u/2: sqrt(0.25*(u^2+v^2)+EPS)
            const float m2  = fmaf(u, u, v * v);
            const float mag = __builtin_amdgcn_sqrtf(fmaf(m2, 0.25f, EPS)) * gw;

            // atan2 in bin units (coeffs pre-scaled by 4/pi)
            const float gxe = u + 2e-10f;
            const float ax = fabsf(gxe), ay = fabsf(v);
            const float mx = fmaxf(ax, ay), mn = fminf(ax, ay);
            const float t = mn * __builtin_amdgcn_rcpf(fmaxf(mx, 1e-35f));
            const float s = t * t;
            float pl = fmaf(s, -0.01492400f, 0.06704059f);
            pl = fmaf(s, pl, -0.14824021f);
            pl = fmaf(s, pl, 0.24642768f);
            pl = fmaf(s, pl, -0.42350528f);
            pl = fmaf(s, pl, 1.27321059f);
            float atb = t * pl;
            atb = (ay > ax)     ? 2.0f - atb : atb;
            atb = (gxe < 0.0f)  ? 4.0f - atb : atb;
            atb = (v   < 0.0f)  ? -atb       : atb;
            const float obig = atb + 8.0f;               // (4, 12]
            const float b0f  = floorf(obig);
            const float w1   = obig - b0f;
            const int bin0 = ((int)b0f) & 7;
            const int bin1 = (bin0 + 1) & 7;
            const float m1 = w1 * mag;
            const float m0 = mag - m1;

            const unsigned short h0 =
                (unsigned short)((__builtin_bit_cast(unsigned int, m0) + 0x8000u) >> 16);
            const unsigned short h1 =
                (unsigned short)((__builtin_bit_cast(unsigned int, m1) + 0x8000u) >> 16);
            *reinterpret_cast<unsigned short*>(angb + bin0 * 2048 + base2 + 2 * i) = h0;
            *reinterpret_cast<unsigned short*>(angb + bin1 * 2048 + base2 + 2 * i) = h1;
        }
    }
    __syncthreads();

    // ---- GEMM1 (MFMA): x-pooling. A = ang (256x32), B^T = WXT (16x32) ----
    {
        const int l = tid & 63, w = tid >> 6, g = l >> 4, n = l & 15;
        const bf16x8 bfrag = *reinterpret_cast<const bf16x8*>(WXT.v + n * 32 + g * 8);
        const f32x4 zacc = {0.f, 0.f, 0.f, 0.f};
        #pragma unroll
        for (int tt = 0; tt < 4; ++tt) {
            const int T = w * 4 + tt;   // row tile 0..15
            const bf16x8 afrag = *reinterpret_cast<const bf16x8*>(
                ang + (T * 16 + n) * 32 + g * 8);
            const f32x4 acc = __builtin_amdgcn_mfma_f32_16x16x32_bf16(afrag, bfrag, zacc, 0, 0, 0);
            if (n < 4) {
                // C layout: row = T*16 + 4g + reg, col = n (=ox)
                const int row = T * 16 + 4 * g;
                const int a = row >> 5, y0 = row & 31;
                *reinterpret_cast<float4*>(r2f + (a * 4 + n) * R2S + y0) =
                    make_float4(acc[0], acc[1], acc[2], acc[3]);
            }
        }
    }
    __syncthreads();

    // ---- phase 2: y-pooling (VALU) ----
    float v = 0.0f;
    if (tid < 128) {
        const int a = tid >> 4, oy = (tid >> 2) & 3, ox = tid & 3;
        const float* rp = r2f + (a * 4 + ox) * R2S;
        const int y0 = oy * 8 - 3;
        #pragma unroll
        for (int k = 0; k < 12; ++k) {
            const float wk = 6.0f - fabsf((float)k - 5.5f);   // compile-time
            const int yy = y0 + k;
            const int yc = (yy < 0) ? 0 : ((yy > 31) ? 31 : yy);
            const float wv = (yy == yc) ? wk : 0.0f;
            v = fmaf(wv, rp[yc], v);
        }
    }

    // ---- normalization chain: l2 -> clip(0,0.2) -> l2 -> l1 -> sqrt(+eps) ----
    float s2 = block_reduce_sum(v * v, scratch, tid);
    v = v / fmaxf(__builtin_amdgcn_sqrtf(s2), 1e-12f);
    v = fminf(fmaxf(v, 0.0f), 0.2f);
    float s2b = block_reduce_sum(v * v, scratch, tid);
    v = v / fmaxf(__builtin_amdgcn_sqrtf(s2b), 1e-12f);
    float s1 = block_reduce_sum(v, scratch, tid);
    v = __builtin_amdgcn_sqrtf(v / fmaxf(s1, 1e-12f) + EPS);

    if (tid < 128) out[(size_t)b * 128 + tid] = v;
}

extern "C" void kernel_launch(void* const* d_in, const int* in_sizes, int n_in,
                              void* d_out, int out_size, void* d_ws, size_t ws_size,
                              hipStream_t stream) {
    const float* in = (const float*)d_in[0];
    float* out = (float*)d_out;
    const int batch = in_sizes[0] / 1024;   // 32*32 per patch
    sift_desc_kernel<<<batch, 256, 0, stream>>>(in, out);
}